// Round 7
// baseline (500.363 us; speedup 1.0000x reference)
//
#include <hip/hip_runtime.h>
#include <math.h>
#include <stdint.h>

// GAT 2-layer: N=50000 nodes, E=800000 edges (+N self loops)
// L1: 512 -> 4 heads x 64 (bf16 MFMA GEMM, att1 fused in epilogue), ELU.
// L2: 256 -> 1 head x 40 (att2 fused in gemm2), log_softmax.
// Softmax edge-weights precomputed edge-parallel (k_pre*); gather kernels
// consume wave-uniform scalar (s, ex) streams -> pure gather+fma.

typedef short bf16x8 __attribute__((ext_vector_type(8)));
typedef float f32x4  __attribute__((ext_vector_type(4)));

static __device__ __forceinline__ float leaky(float x){ return x > 0.f ? x : 0.2f*x; }
static __device__ __forceinline__ unsigned short f2bf(float f){
  uint32_t u = __float_as_uint(f);
  uint32_t r = u + 0x7fffu + ((u >> 16) & 1u);   // RNE
  return (unsigned short)(r >> 16);
}
static __device__ __forceinline__ float bf2f(unsigned short u){
  return __uint_as_float(((uint32_t)u) << 16);
}

// ---------------- convert x -> bf16 (vectorized) ----------------
__global__ void k_cvt_x(const float* __restrict__ x, unsigned short* __restrict__ xb, int n4){
  int i = blockIdx.x*blockDim.x + threadIdx.x;
  if (i >= n4) return;
  float4 v = ((const float4*)x)[i];
  ushort4 o; o.x=f2bf(v.x); o.y=f2bf(v.y); o.z=f2bf(v.z); o.w=f2bf(v.w);
  ((ushort4*)xb)[i] = o;
}

// ---------------- convert+transpose W1 -> w1t bf16; also zero deg ----------------
__global__ void k_cvt_w(const float* __restrict__ W, unsigned short* __restrict__ wt,
                        int* __restrict__ deg, int n){
  int i = blockIdx.x*blockDim.x + threadIdx.x;   // 0..131071
  if (i < n) deg[i] = 0;
  if (i >= 512*256) return;
  int k = i >> 8, c = i & 255;
  wt[c*512 + k] = f2bf(W[i]);
}

// ---------------- count in-degree (incl self loops) ----------------
__global__ void k_count(const int* __restrict__ ei, int E, int n, int* __restrict__ deg){
  int i = blockIdx.x*blockDim.x + threadIdx.x;
  int tot = E + n;
  if (i >= tot) return;
  int dst = (i < E) ? ei[E + i] : (i - E);
  atomicAdd(&deg[dst], 1);
}

// ---------------- multi-block exclusive scan: deg[n] -> rowstart[0..n] ----------------
__global__ __launch_bounds__(256) void k_scan_a(const int* __restrict__ deg,
    int* __restrict__ rowstart, int* __restrict__ bsum, int n){
  __shared__ int sm[256];
  int b = blockIdx.x, t = threadIdx.x;
  int i = b*256 + t;
  int v = (i < n) ? deg[i] : 0;
  sm[t] = v;
  __syncthreads();
  for (int off=1; off<256; off<<=1){
    int u = (t >= off) ? sm[t-off] : 0;
    __syncthreads();
    sm[t] += u;
    __syncthreads();
  }
  if (i < n) rowstart[i+1] = sm[t];
  if (t == 255) bsum[b] = sm[255];
}
__global__ __launch_bounds__(256) void k_scan_b(int* __restrict__ bsum, int nb){
  __shared__ int sm[256];
  int t = threadIdx.x;
  int v = (t < nb) ? bsum[t] : 0;
  sm[t] = v;
  __syncthreads();
  for (int off=1; off<256; off<<=1){
    int u = (t >= off) ? sm[t-off] : 0;
    __syncthreads();
    sm[t] += u;
    __syncthreads();
  }
  if (t < nb) bsum[t] = sm[t] - v;   // exclusive prefix
}
__global__ __launch_bounds__(256) void k_scan_c(int* __restrict__ rowstart,
    const int* __restrict__ bsum, int* __restrict__ cur, int n){
  int b = blockIdx.x, t = threadIdx.x;
  int i = b*256 + t;
  if (i < n){ rowstart[i+1] += bsum[b]; cur[i] = 0; }
  if (i == 0) rowstart[0] = 0;
}

// ---------------- scatter edges into CSR (by dst, stores src) ----------------
__global__ void k_fill(const int* __restrict__ ei, int E, int n,
                       const int* __restrict__ rowstart, int* __restrict__ cur, int* __restrict__ csr){
  int i = blockIdx.x*blockDim.x + threadIdx.x;
  int tot = E + n;
  if (i >= tot) return;
  int src, dst;
  if (i < E){ src = ei[i]; dst = ei[E+i]; } else { src = i - E; dst = src; }
  int pos = atomicAdd(&cur[dst], 1);
  csr[rowstart[dst] + pos] = src;
}

// ---------------- GEMM1 (bf16 MFMA) + fused att1 ----------------
__global__ __launch_bounds__(256) void k_gemm1_mfma(const unsigned short* __restrict__ A,
                                                    const unsigned short* __restrict__ BT,
                                                    const float* __restrict__ SW,
                                                    const float* __restrict__ DW,
                                                    unsigned short* __restrict__ Cb,
                                                    float* __restrict__ as1,
                                                    float* __restrict__ ad1, int M){
  __shared__ __align__(16) unsigned short lA[4*128*8];  // 8 KB
  __shared__ __align__(16) unsigned short lB[4*128*8];  // 8 KB
  const int t = threadIdx.x;
  const int lane = t & 63, w = t >> 6;
  const int wx = w & 1, wy = w >> 1;
  const int row0 = blockIdx.x * 128, col0 = blockIdx.y * 128;

  f32x4 acc[4][4];
  #pragma unroll
  for (int i=0;i<4;i++)
    #pragma unroll
    for (int j=0;j<4;j++)
      #pragma unroll
      for (int r=0;r<4;r++) acc[i][j][r] = 0.f;

  const int c0 = t, c1 = t + 256;
  const int r0 = c0 & 127, kq0 = c0 >> 7;
  const int r1 = c1 & 127, kq1 = c1 >> 7;
  const size_t gA0 = (size_t)min(row0 + r0, M-1)*512 + kq0*8;
  const size_t gA1 = (size_t)min(row0 + r1, M-1)*512 + kq1*8;
  const size_t gB0 = (size_t)(col0 + r0)*512 + kq0*8;
  const size_t gB1 = (size_t)(col0 + r1)*512 + kq1*8;

  const int kq = lane >> 4, li = lane & 15;

  for (int kt = 0; kt < 512; kt += 32){
    __builtin_amdgcn_global_load_lds((const __attribute__((address_space(1))) void*)(A + gA0 + kt),
        (__attribute__((address_space(3))) void*)&lA[c0*8], 16, 0, 0);
    __builtin_amdgcn_global_load_lds((const __attribute__((address_space(1))) void*)(A + gA1 + kt),
        (__attribute__((address_space(3))) void*)&lA[c1*8], 16, 0, 0);
    __builtin_amdgcn_global_load_lds((const __attribute__((address_space(1))) void*)(BT + gB0 + kt),
        (__attribute__((address_space(3))) void*)&lB[c0*8], 16, 0, 0);
    __builtin_amdgcn_global_load_lds((const __attribute__((address_space(1))) void*)(BT + gB1 + kt),
        (__attribute__((address_space(3))) void*)&lB[c1*8], 16, 0, 0);
    __syncthreads();

    bf16x8 af[4], bfr[4];
    #pragma unroll
    for (int i=0;i<4;i++){
      af[i]  = *(const bf16x8*)&lA[(kq*128 + wx*64 + i*16 + li)*8];
      bfr[i] = *(const bf16x8*)&lB[(kq*128 + wy*64 + i*16 + li)*8];
    }
    #pragma unroll
    for (int i=0;i<4;i++)
      #pragma unroll
      for (int j=0;j<4;j++)
        acc[i][j] = __builtin_amdgcn_mfma_f32_16x16x32_bf16(af[i], bfr[j], acc[i][j], 0, 0, 0);
    __syncthreads();
  }

  // epilogue 1: C store. C/D map col=lane&15, row=(lane>>4)*4+reg
  #pragma unroll
  for (int i=0;i<4;i++){
    #pragma unroll
    for (int r=0;r<4;r++){
      int row = row0 + wx*64 + i*16 + kq*4 + r;
      if (row < M){
        #pragma unroll
        for (int j=0;j<4;j++)
          Cb[(size_t)row*256 + col0 + wy*64 + j*16 + li] = f2bf(acc[i][j][r]);
      }
    }
  }

  // epilogue 2: fused att1 dots for head hw (this wave's 64-col span)
  const int hw = (int)blockIdx.y*2 + wy;
  float sv[4], dv[4];
  #pragma unroll
  for (int j=0;j<4;j++){
    sv[j] = SW[hw*64 + j*16 + li];
    dv[j] = DW[hw*64 + j*16 + li];
  }
  #pragma unroll
  for (int i=0;i<4;i++){
    #pragma unroll
    for (int r=0;r<4;r++){
      float ps = acc[i][0][r]*sv[0] + acc[i][1][r]*sv[1] + acc[i][2][r]*sv[2] + acc[i][3][r]*sv[3];
      float pd = acc[i][0][r]*dv[0] + acc[i][1][r]*dv[1] + acc[i][2][r]*dv[2] + acc[i][3][r]*dv[3];
      #pragma unroll
      for (int o=1;o<16;o<<=1){ ps += __shfl_xor(ps,o); pd += __shfl_xor(pd,o); }
      int row = row0 + wx*64 + i*16 + kq*4 + r;
      if (li == 0 && row < M){
        as1[row*4 + hw] = ps;
        ad1[row*4 + hw] = pd;
      }
    }
  }
}

// ---------------- pre-pass L1: per-edge ex (4 heads) + per-node 1/sum ----------------
// wave per node; lane layout (edge,head) = (lane>>2, lane&3)
__global__ __launch_bounds__(256) void k_pre1(const float* __restrict__ as1,
    const float* __restrict__ ad1, const int* __restrict__ rowstart,
    const int* __restrict__ csr, float* __restrict__ exbuf, float* __restrict__ inv1, int n){
  int lane = threadIdx.x & 63;
  int node = blockIdx.x*4 + (threadIdx.x >> 6);
  if (node >= n) return;
  int lo = rowstart[node], hi = rowstart[node+1];
  int jj = lane >> 2, hh = lane & 3;
  float adh = ad1[node*4 + hh];
  float m = -INFINITY;
  for (int c = lo + jj; c < hi; c += 16)
    m = fmaxf(m, leaky(as1[csr[c]*4 + hh] + adh));
  #pragma unroll
  for (int o=4;o<64;o<<=1) m = fmaxf(m, __shfl_xor(m,o));
  float psum = 0.f;
  for (int c = lo + jj; c < hi; c += 16){
    float ex = __expf(leaky(as1[csr[c]*4 + hh] + adh) - m);
    exbuf[(size_t)c*4 + hh] = ex;     // contiguous 256B per chunk
    psum += ex;
  }
  #pragma unroll
  for (int o=4;o<64;o<<=1) psum += __shfl_xor(psum,o);
  if (jj == 0) inv1[node*4 + hh] = 1.f/(psum + 1e-16f);
}

// ---------------- aggregation L1: pure gather+fma, + bias + ELU -> bf16 ----------
__global__ __launch_bounds__(256) void k_agg1(const unsigned short* __restrict__ h1b,
    const float* __restrict__ exbuf, const float* __restrict__ inv1,
    const int* __restrict__ rowstart, const int* __restrict__ csr,
    const float* __restrict__ b1, unsigned short* __restrict__ hactb, int n){
  int lane = threadIdx.x & 63;
  int node = blockIdx.x*4 + (threadIdx.x >> 6);
  if (node >= n) return;
  int lo = __builtin_amdgcn_readfirstlane(rowstart[node]);
  int hi = __builtin_amdgcn_readfirstlane(rowstart[node+1]);
  int h = lane >> 4;
  const float* exb = exbuf + h;          // lane reads exbuf[e*4+h]
  float ax=0.f, ay=0.f, az=0.f, aw=0.f;
  int e = lo;
  for (; e + 3 < hi; e += 4){
    int s0 = csr[e], s1 = csr[e+1], s2 = csr[e+2], s3 = csr[e+3];   // scalar
    float e0 = exb[(size_t)e*4],     e1 = exb[(size_t)(e+1)*4],
          e2 = exb[(size_t)(e+2)*4], e3 = exb[(size_t)(e+3)*4];
    ushort4 u0 = *(const ushort4*)(h1b + (size_t)s0*256 + lane*4);
    ushort4 u1 = *(const ushort4*)(h1b + (size_t)s1*256 + lane*4);
    ushort4 u2 = *(const ushort4*)(h1b + (size_t)s2*256 + lane*4);
    ushort4 u3 = *(const ushort4*)(h1b + (size_t)s3*256 + lane*4);
    ax += e0*bf2f(u0.x) + e1*bf2f(u1.x) + e2*bf2f(u2.x) + e3*bf2f(u3.x);
    ay += e0*bf2f(u0.y) + e1*bf2f(u1.y) + e2*bf2f(u2.y) + e3*bf2f(u3.y);
    az += e0*bf2f(u0.z) + e1*bf2f(u1.z) + e2*bf2f(u2.z) + e3*bf2f(u3.z);
    aw += e0*bf2f(u0.w) + e1*bf2f(u1.w) + e2*bf2f(u2.w) + e3*bf2f(u3.w);
  }
  for (; e < hi; ++e){
    int s0 = csr[e];
    float e0 = exb[(size_t)e*4];
    ushort4 u0 = *(const ushort4*)(h1b + (size_t)s0*256 + lane*4);
    ax += e0*bf2f(u0.x); ay += e0*bf2f(u0.y); az += e0*bf2f(u0.z); aw += e0*bf2f(u0.w);
  }
  float inv = inv1[node*4 + h];
  float4 bv = *(const float4*)(b1 + lane*4);
  float o0 = ax*inv + bv.x, o1 = ay*inv + bv.y, o2 = az*inv + bv.z, o3 = aw*inv + bv.w;
  ushort4 r;
  r.x = f2bf(o0 > 0.f ? o0 : expm1f(o0));
  r.y = f2bf(o1 > 0.f ? o1 : expm1f(o1));
  r.z = f2bf(o2 > 0.f ? o2 : expm1f(o2));
  r.w = f2bf(o3 > 0.f ? o3 : expm1f(o3));
  *(ushort4*)(hactb + (size_t)node*256 + lane*4) = r;
}

// ---------------- GEMM2: hact[M,256]bf16 @ W2[256,40]f32 -> h2b[M,40]bf16 ------------
// + fused att2: as2/ad2 [N] via LDS reduce.
__global__ __launch_bounds__(256) void k_gemm2(const unsigned short* __restrict__ A,
    const float* __restrict__ B, const float* __restrict__ sw, const float* __restrict__ dw,
    unsigned short* __restrict__ Cb, float* __restrict__ as2, float* __restrict__ ad2, int M){
  __shared__ float Xl[32][129];       // pad -> conflict-free column reads
  __shared__ float Wl[128*40];
  __shared__ float Sps[32][8], Spd[32][8];
  int t = threadIdx.x;
  int row0 = blockIdx.x*32;
  int r = t & 31, g = t >> 5;         // g in 0..7 -> cols g*5 .. g*5+4
  float acc[5] = {0,0,0,0,0};
  for (int kt=0; kt<256; kt+=128){
    for (int i=t; i<1280; i+=256)
      *(float4*)&Wl[i*4] = *(const float4*)(B + kt*40 + i*4);
    for (int i=t; i<512; i+=256){     // 32 rows x 128 k, 8 bf16 per chunk
      int rr = i >> 4, k8 = i & 15;
      int grow = row0 + rr; if (grow >= M) grow = M-1;
      uint4 v = *(const uint4*)(A + (size_t)grow*256 + kt + k8*8);
      float* xp = &Xl[rr][k8*8];
      xp[0] = __uint_as_float(v.x << 16); xp[1] = __uint_as_float(v.x & 0xffff0000u);
      xp[2] = __uint_as_float(v.y << 16); xp[3] = __uint_as_float(v.y & 0xffff0000u);
      xp[4] = __uint_as_float(v.z << 16); xp[5] = __uint_as_float(v.z & 0xffff0000u);
      xp[6] = __uint_as_float(v.w << 16); xp[7] = __uint_as_float(v.w & 0xffff0000u);
    }
    __syncthreads();
    #pragma unroll 4
    for (int k=0;k<128;++k){
      float a = Xl[r][k];
      const float* wp = &Wl[k*40 + g*5];
      #pragma unroll
      for (int j=0;j<5;++j) acc[j] += a * wp[j];
    }
    __syncthreads();
  }
  int grow = row0 + r;
  float ps = 0.f, pd = 0.f;
  #pragma unroll
  for (int j=0;j<5;++j){
    ps += acc[j] * sw[g*5+j];
    pd += acc[j] * dw[g*5+j];
  }
  Sps[r][g] = ps; Spd[r][g] = pd;
  if (grow < M){
    #pragma unroll
    for (int j=0;j<5;++j) Cb[(size_t)grow*40 + g*5 + j] = f2bf(acc[j]);
  }
  __syncthreads();
  if (t < 32){
    float a = 0.f, b = 0.f;
    #pragma unroll
    for (int g2=0; g2<8; ++g2){ a += Sps[t][g2]; b += Spd[t][g2]; }
    int rw = row0 + t;
    if (rw < M){ as2[rw] = a; ad2[rw] = b; }
  }
}

// ---------------- pre-pass L2: per-edge ex + per-node 1/sum ----------------
__global__ __launch_bounds__(256) void k_pre2(const float* __restrict__ as2,
    const float* __restrict__ ad2, const int* __restrict__ rowstart,
    const int* __restrict__ csr, float* __restrict__ ex2, float* __restrict__ inv2, int n){
  int lane = threadIdx.x & 63;
  int node = blockIdx.x*4 + (threadIdx.x >> 6);
  if (node >= n) return;
  int lo = rowstart[node], hi = rowstart[node+1];
  float adn = ad2[node];
  float m = -INFINITY;
  for (int e = lo + lane; e < hi; e += 64)
    m = fmaxf(m, leaky(as2[csr[e]] + adn));
  #pragma unroll
  for (int o=1;o<64;o<<=1) m = fmaxf(m, __shfl_xor(m,o));
  float psum = 0.f;
  for (int e = lo + lane; e < hi; e += 64){
    float ex = __expf(leaky(as2[csr[e]] + adn) - m);
    ex2[e] = ex;
    psum += ex;
  }
  #pragma unroll
  for (int o=1;o<64;o<<=1) psum += __shfl_xor(psum,o);
  if (lane == 0) inv2[node] = 1.f/(psum + 1e-16f);
}

// ---------------- aggregation L2: pure gather+fma, + bias + log_softmax ----------
__global__ __launch_bounds__(256) void k_agg2(const unsigned short* __restrict__ h2b,
    const float* __restrict__ ex2, const float* __restrict__ inv2,
    const int* __restrict__ rowstart, const int* __restrict__ csr,
    const float* __restrict__ b2, float* __restrict__ out, int n){
  int lane = threadIdx.x & 63;
  int node = blockIdx.x*4 + (threadIdx.x >> 6);
  if (node >= n) return;
  int lo = __builtin_amdgcn_readfirstlane(rowstart[node]);
  int hi = __builtin_amdgcn_readfirstlane(rowstart[node+1]);
  bool act = lane < 40;
  float acc = 0.f;
  int e = lo;
  for (; e + 3 < hi; e += 4){
    int s0 = csr[e], s1 = csr[e+1], s2 = csr[e+2], s3 = csr[e+3];   // scalar
    float e0 = ex2[e], e1 = ex2[e+1], e2 = ex2[e+2], e3 = ex2[e+3]; // scalar
    float h0 = act ? bf2f(h2b[(size_t)s0*40 + lane]) : 0.f;
    float h1 = act ? bf2f(h2b[(size_t)s1*40 + lane]) : 0.f;
    float h2 = act ? bf2f(h2b[(size_t)s2*40 + lane]) : 0.f;
    float h3 = act ? bf2f(h2b[(size_t)s3*40 + lane]) : 0.f;
    acc += e0*h0 + e1*h1 + e2*h2 + e3*h3;
  }
  for (; e < hi; ++e){
    int s0 = csr[e]; float e0 = ex2[e];
    acc += e0 * (act ? bf2f(h2b[(size_t)s0*40 + lane]) : 0.f);
  }
  float ov = acc*inv2[node] + (act ? b2[lane] : 0.f);
  float v = act ? ov : -INFINITY;
  float mx = v;
  #pragma unroll
  for (int o=1;o<64;o<<=1) mx = fmaxf(mx, __shfl_xor(mx,o));
  float ev = act ? __expf(ov - mx) : 0.f;
  float se = ev;
  #pragma unroll
  for (int o=1;o<64;o<<=1) se += __shfl_xor(se,o);
  if (act) out[(size_t)node*40 + lane] = (ov - mx) - __logf(se);
}

extern "C" void kernel_launch(void* const* d_in, const int* in_sizes, int n_in,
                              void* d_out, int out_size, void* d_ws, size_t ws_size,
                              hipStream_t stream){
  const float* x   = (const float*)d_in[0];
  const int*   ei  = (const int*)d_in[1];     // [2,E] int32 (harness contract)
  const float* W1  = (const float*)d_in[2];
  const float* s1w = (const float*)d_in[3];
  const float* d1w = (const float*)d_in[4];
  const float* b1  = (const float*)d_in[5];
  const float* W2  = (const float*)d_in[6];
  const float* s2w = (const float*)d_in[7];
  const float* d2w = (const float*)d_in[8];
  const float* b2  = (const float*)d_in[9];
  float* out = (float*)d_out;

  const int N  = in_sizes[0] / 512;
  const int E  = in_sizes[1] / 2;
  const int Et = E + N;

  // workspace carve-out (~112 MB)
  float* f = (float*)d_ws;
  unsigned short* h1b   = (unsigned short*)f;  f += (size_t)N*128;   // [N][256] bf16
  unsigned short* hactb = (unsigned short*)f;  f += (size_t)N*128;   // [N][256] bf16
  float* as1  = f;  f += (size_t)N*4;
  float* ad1  = f;  f += (size_t)N*4;
  float* as2  = f;  f += N;
  float* ad2  = f;  f += N;
  float* inv1 = f;  f += (size_t)N*4;
  float* inv2 = f;  f += N;
  unsigned short* w1t = (unsigned short*)f;  f += 256*512/2;         // [256][512] bf16
  unsigned short* xb  = (unsigned short*)f;  f += (size_t)N*256;     // [N][512] bf16 (51.2 MB)
  // aliases into dead xb region:
  unsigned short* h2b   = xb;                          // gemm2->agg2 ([N][40] bf16, 4 MB)
  float*          exbuf = (float*)(xb + (size_t)4*1024*1024);        // pre1->agg1 ([Et][4] f32, 13.6 MB)
  float*          ex2   = (float*)(xb + (size_t)12*1024*1024);       // pre2->agg2 ([Et] f32, 3.4 MB)
  int* ip = (int*)f;
  int* rowstart = ip;  ip += (N + 4) & ~3;
  int* deg      = ip;  ip += N;
  int* cur      = ip;  ip += N;
  int* csr      = ip;  ip += Et;
  int* bsum     = ip;  ip += 256;

  int nb4 = (N + 3) / 4;
  int n4  = (N*512)/4;
  int nbs = (N + 255) / 256;                 // scan blocks (196 <= 256)
  k_cvt_x<<<(n4+255)/256, 256, 0, stream>>>(x, xb, n4);
  k_cvt_w<<<512, 256, 0, stream>>>(W1, w1t, deg, N);
  k_count<<<(Et+255)/256, 256, 0, stream>>>(ei, E, N, deg);
  k_scan_a<<<nbs, 256, 0, stream>>>(deg, rowstart, bsum, N);
  k_scan_b<<<1, 256, 0, stream>>>(bsum, nbs);
  k_scan_c<<<nbs, 256, 0, stream>>>(rowstart, bsum, cur, N);
  k_fill <<<(Et+255)/256, 256, 0, stream>>>(ei, E, N, rowstart, cur, csr);
  k_gemm1_mfma<<<dim3((N+127)/128, 2), 256, 0, stream>>>(xb, w1t, s1w, d1w, h1b, as1, ad1, N);
  k_pre1 <<<nb4, 256, 0, stream>>>(as1, ad1, rowstart, csr, exbuf, inv1, N);
  k_agg1 <<<nb4, 256, 0, stream>>>(h1b, exbuf, inv1, rowstart, csr, b1, hactb, N);
  k_gemm2<<<(N+31)/32, 256, 0, stream>>>(hactb, W2, s2w, d2w, h2b, as2, ad2, N);
  k_pre2 <<<nb4, 256, 0, stream>>>(as2, ad2, rowstart, csr, ex2, inv2, N);
  k_agg2 <<<nb4, 256, 0, stream>>>(h2b, ex2, inv2, rowstart, csr, b2, out, N);
}

// Round 8
// 484.341 us; speedup vs baseline: 1.0331x; 1.0331x over previous
//
#include <hip/hip_runtime.h>
#include <math.h>
#include <stdint.h>

// GAT 2-layer: N=50000 nodes, E=800000 edges (+N self loops)
// L1: 512 -> 4 heads x 64 (bf16 MFMA GEMM, att1 fused in epilogue), ELU.
// L2: 256 -> 1 head x 40 (att2 fused in gemm2), log_softmax.
// Softmax WITHOUT max-shift (logits ~N(0,1), clamped at 80 for safety):
// per-edge exp computed in k_fill (L1) / k_pre2 (L2); agg kernels consume
// wave-uniform scalar (csr, ex) streams and accumulate the denominator inline.

typedef short bf16x8 __attribute__((ext_vector_type(8)));
typedef float f32x4  __attribute__((ext_vector_type(4)));

static __device__ __forceinline__ float leaky(float x){ return x > 0.f ? x : 0.2f*x; }
static __device__ __forceinline__ unsigned short f2bf(float f){
  uint32_t u = __float_as_uint(f);
  uint32_t r = u + 0x7fffu + ((u >> 16) & 1u);   // RNE
  return (unsigned short)(r >> 16);
}
static __device__ __forceinline__ float bf2f(unsigned short u){
  return __uint_as_float(((uint32_t)u) << 16);
}

// ---------------- convert x -> bf16 (vectorized) ----------------
__global__ void k_cvt_x(const float* __restrict__ x, unsigned short* __restrict__ xb, int n4){
  int i = blockIdx.x*blockDim.x + threadIdx.x;
  if (i >= n4) return;
  float4 v = ((const float4*)x)[i];
  ushort4 o; o.x=f2bf(v.x); o.y=f2bf(v.y); o.z=f2bf(v.z); o.w=f2bf(v.w);
  ((ushort4*)xb)[i] = o;
}

// ---------------- convert+transpose W1 -> w1t bf16; also zero deg ----------------
__global__ void k_cvt_w(const float* __restrict__ W, unsigned short* __restrict__ wt,
                        int* __restrict__ deg, int n){
  int i = blockIdx.x*blockDim.x + threadIdx.x;   // 0..131071
  if (i < n) deg[i] = 0;
  if (i >= 512*256) return;
  int k = i >> 8, c = i & 255;
  wt[c*512 + k] = f2bf(W[i]);
}

// ---------------- count in-degree (incl self loops) ----------------
__global__ void k_count(const int* __restrict__ ei, int E, int n, int* __restrict__ deg){
  int i = blockIdx.x*blockDim.x + threadIdx.x;
  int tot = E + n;
  if (i >= tot) return;
  int dst = (i < E) ? ei[E + i] : (i - E);
  atomicAdd(&deg[dst], 1);
}

// ---------------- multi-block exclusive scan: deg[n] -> rowstart[0..n] ----------------
__global__ __launch_bounds__(256) void k_scan_a(const int* __restrict__ deg,
    int* __restrict__ rowstart, int* __restrict__ bsum, int n){
  __shared__ int sm[256];
  int b = blockIdx.x, t = threadIdx.x;
  int i = b*256 + t;
  int v = (i < n) ? deg[i] : 0;
  sm[t] = v;
  __syncthreads();
  for (int off=1; off<256; off<<=1){
    int u = (t >= off) ? sm[t-off] : 0;
    __syncthreads();
    sm[t] += u;
    __syncthreads();
  }
  if (i < n) rowstart[i+1] = sm[t];
  if (t == 255) bsum[b] = sm[255];
}
__global__ __launch_bounds__(256) void k_scan_b(int* __restrict__ bsum, int nb){
  __shared__ int sm[256];
  int t = threadIdx.x;
  int v = (t < nb) ? bsum[t] : 0;
  sm[t] = v;
  __syncthreads();
  for (int off=1; off<256; off<<=1){
    int u = (t >= off) ? sm[t-off] : 0;
    __syncthreads();
    sm[t] += u;
    __syncthreads();
  }
  if (t < nb) bsum[t] = sm[t] - v;   // exclusive prefix
}
__global__ __launch_bounds__(256) void k_scan_c(int* __restrict__ rowstart,
    const int* __restrict__ bsum, int* __restrict__ cur, int n){
  int b = blockIdx.x, t = threadIdx.x;
  int i = b*256 + t;
  if (i < n){ rowstart[i+1] += bsum[b]; cur[i] = 0; }
  if (i == 0) rowstart[0] = 0;
}

// ---------------- GEMM1 (bf16 MFMA) + fused att1 ----------------
__global__ __launch_bounds__(256) void k_gemm1_mfma(const unsigned short* __restrict__ A,
                                                    const unsigned short* __restrict__ BT,
                                                    const float* __restrict__ SW,
                                                    const float* __restrict__ DW,
                                                    unsigned short* __restrict__ Cb,
                                                    float* __restrict__ as1,
                                                    float* __restrict__ ad1, int M){
  __shared__ __align__(16) unsigned short lA[4*128*8];  // 8 KB
  __shared__ __align__(16) unsigned short lB[4*128*8];  // 8 KB
  const int t = threadIdx.x;
  const int lane = t & 63, w = t >> 6;
  const int wx = w & 1, wy = w >> 1;
  const int row0 = blockIdx.x * 128, col0 = blockIdx.y * 128;

  f32x4 acc[4][4];
  #pragma unroll
  for (int i=0;i<4;i++)
    #pragma unroll
    for (int j=0;j<4;j++)
      #pragma unroll
      for (int r=0;r<4;r++) acc[i][j][r] = 0.f;

  const int c0 = t, c1 = t + 256;
  const int r0 = c0 & 127, kq0 = c0 >> 7;
  const int r1 = c1 & 127, kq1 = c1 >> 7;
  const size_t gA0 = (size_t)min(row0 + r0, M-1)*512 + kq0*8;
  const size_t gA1 = (size_t)min(row0 + r1, M-1)*512 + kq1*8;
  const size_t gB0 = (size_t)(col0 + r0)*512 + kq0*8;
  const size_t gB1 = (size_t)(col0 + r1)*512 + kq1*8;

  const int kq = lane >> 4, li = lane & 15;

  for (int kt = 0; kt < 512; kt += 32){
    __builtin_amdgcn_global_load_lds((const __attribute__((address_space(1))) void*)(A + gA0 + kt),
        (__attribute__((address_space(3))) void*)&lA[c0*8], 16, 0, 0);
    __builtin_amdgcn_global_load_lds((const __attribute__((address_space(1))) void*)(A + gA1 + kt),
        (__attribute__((address_space(3))) void*)&lA[c1*8], 16, 0, 0);
    __builtin_amdgcn_global_load_lds((const __attribute__((address_space(1))) void*)(BT + gB0 + kt),
        (__attribute__((address_space(3))) void*)&lB[c0*8], 16, 0, 0);
    __builtin_amdgcn_global_load_lds((const __attribute__((address_space(1))) void*)(BT + gB1 + kt),
        (__attribute__((address_space(3))) void*)&lB[c1*8], 16, 0, 0);
    __syncthreads();

    bf16x8 af[4], bfr[4];
    #pragma unroll
    for (int i=0;i<4;i++){
      af[i]  = *(const bf16x8*)&lA[(kq*128 + wx*64 + i*16 + li)*8];
      bfr[i] = *(const bf16x8*)&lB[(kq*128 + wy*64 + i*16 + li)*8];
    }
    #pragma unroll
    for (int i=0;i<4;i++)
      #pragma unroll
      for (int j=0;j<4;j++)
        acc[i][j] = __builtin_amdgcn_mfma_f32_16x16x32_bf16(af[i], bfr[j], acc[i][j], 0, 0, 0);
    __syncthreads();
  }

  // epilogue 1: C store. C/D map col=lane&15, row=(lane>>4)*4+reg
  #pragma unroll
  for (int i=0;i<4;i++){
    #pragma unroll
    for (int r=0;r<4;r++){
      int row = row0 + wx*64 + i*16 + kq*4 + r;
      if (row < M){
        #pragma unroll
        for (int j=0;j<4;j++)
          Cb[(size_t)row*256 + col0 + wy*64 + j*16 + li] = f2bf(acc[i][j][r]);
      }
    }
  }

  // epilogue 2: fused att1 dots for head hw (this wave's 64-col span)
  const int hw = (int)blockIdx.y*2 + wy;
  float sv[4], dv[4];
  #pragma unroll
  for (int j=0;j<4;j++){
    sv[j] = SW[hw*64 + j*16 + li];
    dv[j] = DW[hw*64 + j*16 + li];
  }
  #pragma unroll
  for (int i=0;i<4;i++){
    #pragma unroll
    for (int r=0;r<4;r++){
      float ps = acc[i][0][r]*sv[0] + acc[i][1][r]*sv[1] + acc[i][2][r]*sv[2] + acc[i][3][r]*sv[3];
      float pd = acc[i][0][r]*dv[0] + acc[i][1][r]*dv[1] + acc[i][2][r]*dv[2] + acc[i][3][r]*dv[3];
      #pragma unroll
      for (int o=1;o<16;o<<=1){ ps += __shfl_xor(ps,o); pd += __shfl_xor(pd,o); }
      int row = row0 + wx*64 + i*16 + kq*4 + r;
      if (li == 0 && row < M){
        as1[row*4 + hw] = ps;
        ad1[row*4 + hw] = pd;
      }
    }
  }
}

// ---------------- scatter edges into CSR + compute per-edge ex (4 heads) ----------
__global__ void k_fill(const int* __restrict__ ei, int E, int n,
                       const int* __restrict__ rowstart, int* __restrict__ cur,
                       int* __restrict__ csr,
                       const float* __restrict__ as1, const float* __restrict__ ad1,
                       float* __restrict__ exbuf){
  int i = blockIdx.x*blockDim.x + threadIdx.x;
  int tot = E + n;
  if (i >= tot) return;
  int src, dst;
  if (i < E){ src = ei[i]; dst = ei[E+i]; } else { src = i - E; dst = src; }
  int pos = atomicAdd(&cur[dst], 1);
  int slot = rowstart[dst] + pos;
  csr[slot] = src;
  float4 a = *(const float4*)(as1 + (size_t)src*4);
  float4 d = *(const float4*)(ad1 + (size_t)dst*4);
  float4 ex;
  ex.x = __expf(fminf(leaky(a.x + d.x), 80.f));
  ex.y = __expf(fminf(leaky(a.y + d.y), 80.f));
  ex.z = __expf(fminf(leaky(a.z + d.z), 80.f));
  ex.w = __expf(fminf(leaky(a.w + d.w), 80.f));
  *(float4*)(exbuf + (size_t)slot*4) = ex;
}

// ---------------- aggregation L1: pure gather+fma, denom inline, + bias + ELU ----------
__global__ __launch_bounds__(256) void k_agg1(const unsigned short* __restrict__ h1b,
    const float* __restrict__ exbuf,
    const int* __restrict__ rowstart, const int* __restrict__ csr,
    const float* __restrict__ b1, unsigned short* __restrict__ hactb, int n){
  int lane = threadIdx.x & 63;
  int node = blockIdx.x*4 + (threadIdx.x >> 6);
  if (node >= n) return;
  int lo = __builtin_amdgcn_readfirstlane(rowstart[node]);
  int hi = __builtin_amdgcn_readfirstlane(rowstart[node+1]);
  int h = lane >> 4;
  const float* exb = exbuf + h;          // lane reads exbuf[e*4+h]
  float ax=0.f, ay=0.f, az=0.f, aw=0.f, psum=0.f;
  int e = lo;
  for (; e + 7 < hi; e += 8){
    int s0 = csr[e],   s1 = csr[e+1], s2 = csr[e+2], s3 = csr[e+3];   // scalar
    int s4 = csr[e+4], s5 = csr[e+5], s6 = csr[e+6], s7 = csr[e+7];
    float e0 = exb[(size_t)e*4],     e1 = exb[(size_t)(e+1)*4],
          e2 = exb[(size_t)(e+2)*4], e3 = exb[(size_t)(e+3)*4],
          e4 = exb[(size_t)(e+4)*4], e5 = exb[(size_t)(e+5)*4],
          e6 = exb[(size_t)(e+6)*4], e7 = exb[(size_t)(e+7)*4];
    ushort4 u0 = *(const ushort4*)(h1b + (size_t)s0*256 + lane*4);
    ushort4 u1 = *(const ushort4*)(h1b + (size_t)s1*256 + lane*4);
    ushort4 u2 = *(const ushort4*)(h1b + (size_t)s2*256 + lane*4);
    ushort4 u3 = *(const ushort4*)(h1b + (size_t)s3*256 + lane*4);
    ushort4 u4 = *(const ushort4*)(h1b + (size_t)s4*256 + lane*4);
    ushort4 u5 = *(const ushort4*)(h1b + (size_t)s5*256 + lane*4);
    ushort4 u6 = *(const ushort4*)(h1b + (size_t)s6*256 + lane*4);
    ushort4 u7 = *(const ushort4*)(h1b + (size_t)s7*256 + lane*4);
    ax += e0*bf2f(u0.x) + e1*bf2f(u1.x) + e2*bf2f(u2.x) + e3*bf2f(u3.x)
        + e4*bf2f(u4.x) + e5*bf2f(u5.x) + e6*bf2f(u6.x) + e7*bf2f(u7.x);
    ay += e0*bf2f(u0.y) + e1*bf2f(u1.y) + e2*bf2f(u2.y) + e3*bf2f(u3.y)
        + e4*bf2f(u4.y) + e5*bf2f(u5.y) + e6*bf2f(u6.y) + e7*bf2f(u7.y);
    az += e0*bf2f(u0.z) + e1*bf2f(u1.z) + e2*bf2f(u2.z) + e3*bf2f(u3.z)
        + e4*bf2f(u4.z) + e5*bf2f(u5.z) + e6*bf2f(u6.z) + e7*bf2f(u7.z);
    aw += e0*bf2f(u0.w) + e1*bf2f(u1.w) + e2*bf2f(u2.w) + e3*bf2f(u3.w)
        + e4*bf2f(u4.w) + e5*bf2f(u5.w) + e6*bf2f(u6.w) + e7*bf2f(u7.w);
    psum += (e0+e1+e2+e3) + (e4+e5+e6+e7);
  }
  for (; e < hi; ++e){
    int s0 = csr[e];
    float e0 = exb[(size_t)e*4];
    ushort4 u0 = *(const ushort4*)(h1b + (size_t)s0*256 + lane*4);
    ax += e0*bf2f(u0.x); ay += e0*bf2f(u0.y); az += e0*bf2f(u0.z); aw += e0*bf2f(u0.w);
    psum += e0;
  }
  float inv = 1.f/(psum + 1e-16f);
  float4 bv = *(const float4*)(b1 + lane*4);
  float o0 = ax*inv + bv.x, o1 = ay*inv + bv.y, o2 = az*inv + bv.z, o3 = aw*inv + bv.w;
  ushort4 r;
  r.x = f2bf(o0 > 0.f ? o0 : expm1f(o0));
  r.y = f2bf(o1 > 0.f ? o1 : expm1f(o1));
  r.z = f2bf(o2 > 0.f ? o2 : expm1f(o2));
  r.w = f2bf(o3 > 0.f ? o3 : expm1f(o3));
  *(ushort4*)(hactb + (size_t)node*256 + lane*4) = r;
}

// ---------------- GEMM2: hact[M,256]bf16 @ W2[256,40]f32 -> h2b[M,40]bf16 ------------
// + fused att2: as2/ad2 [N] via LDS reduce.
__global__ __launch_bounds__(256) void k_gemm2(const unsigned short* __restrict__ A,
    const float* __restrict__ B, const float* __restrict__ sw, const float* __restrict__ dw,
    unsigned short* __restrict__ Cb, float* __restrict__ as2, float* __restrict__ ad2, int M){
  __shared__ float Xl[32][129];       // pad -> conflict-free column reads
  __shared__ float Wl[128*40];
  __shared__ float Sps[32][8], Spd[32][8];
  int t = threadIdx.x;
  int row0 = blockIdx.x*32;
  int r = t & 31, g = t >> 5;         // g in 0..7 -> cols g*5 .. g*5+4
  float acc[5] = {0,0,0,0,0};
  for (int kt=0; kt<256; kt+=128){
    for (int i=t; i<1280; i+=256)
      *(float4*)&Wl[i*4] = *(const float4*)(B + kt*40 + i*4);
    for (int i=t; i<512; i+=256){     // 32 rows x 128 k, 8 bf16 per chunk
      int rr = i >> 4, k8 = i & 15;
      int grow = row0 + rr; if (grow >= M) grow = M-1;
      uint4 v = *(const uint4*)(A + (size_t)grow*256 + kt + k8*8);
      float* xp = &Xl[rr][k8*8];
      xp[0] = __uint_as_float(v.x << 16); xp[1] = __uint_as_float(v.x & 0xffff0000u);
      xp[2] = __uint_as_float(v.y << 16); xp[3] = __uint_as_float(v.y & 0xffff0000u);
      xp[4] = __uint_as_float(v.z << 16); xp[5] = __uint_as_float(v.z & 0xffff0000u);
      xp[6] = __uint_as_float(v.w << 16); xp[7] = __uint_as_float(v.w & 0xffff0000u);
    }
    __syncthreads();
    #pragma unroll 4
    for (int k=0;k<128;++k){
      float a = Xl[r][k];
      const float* wp = &Wl[k*40 + g*5];
      #pragma unroll
      for (int j=0;j<5;++j) acc[j] += a * wp[j];
    }
    __syncthreads();
  }
  int grow = row0 + r;
  float ps = 0.f, pd = 0.f;
  #pragma unroll
  for (int j=0;j<5;++j){
    ps += acc[j] * sw[g*5+j];
    pd += acc[j] * dw[g*5+j];
  }
  Sps[r][g] = ps; Spd[r][g] = pd;
  if (grow < M){
    #pragma unroll
    for (int j=0;j<5;++j) Cb[(size_t)grow*40 + g*5 + j] = f2bf(acc[j]);
  }
  __syncthreads();
  if (t < 32){
    float a = 0.f, b = 0.f;
    #pragma unroll
    for (int g2=0; g2<8; ++g2){ a += Sps[t][g2]; b += Spd[t][g2]; }
    int rw = row0 + t;
    if (rw < M){ as2[rw] = a; ad2[rw] = b; }
  }
}

// ---------------- pre-pass L2: per-edge ex (no max, single pass) ----------------
__global__ __launch_bounds__(256) void k_pre2(const float* __restrict__ as2,
    const float* __restrict__ ad2, const int* __restrict__ rowstart,
    const int* __restrict__ csr, float* __restrict__ ex2, int n){
  int lane = threadIdx.x & 63;
  int node = blockIdx.x*4 + (threadIdx.x >> 6);
  if (node >= n) return;
  int lo = rowstart[node], hi = rowstart[node+1];
  float adn = ad2[node];
  for (int e = lo + lane; e < hi; e += 64)
    ex2[e] = __expf(fminf(leaky(as2[csr[e]] + adn), 80.f));
}

// ---------------- aggregation L2: gather+fma, denom inline, + bias + log_softmax ------
__global__ __launch_bounds__(256) void k_agg2(const unsigned short* __restrict__ h2b,
    const float* __restrict__ ex2,
    const int* __restrict__ rowstart, const int* __restrict__ csr,
    const float* __restrict__ b2, float* __restrict__ out, int n){
  int lane = threadIdx.x & 63;
  int node = blockIdx.x*4 + (threadIdx.x >> 6);
  if (node >= n) return;
  int lo = __builtin_amdgcn_readfirstlane(rowstart[node]);
  int hi = __builtin_amdgcn_readfirstlane(rowstart[node+1]);
  bool act = lane < 40;
  float acc = 0.f, psum = 0.f;
  int e = lo;
  for (; e + 7 < hi; e += 8){
    int s0 = csr[e],   s1 = csr[e+1], s2 = csr[e+2], s3 = csr[e+3];   // scalar
    int s4 = csr[e+4], s5 = csr[e+5], s6 = csr[e+6], s7 = csr[e+7];
    float e0 = ex2[e],   e1 = ex2[e+1], e2 = ex2[e+2], e3 = ex2[e+3]; // scalar
    float e4 = ex2[e+4], e5 = ex2[e+5], e6 = ex2[e+6], e7 = ex2[e+7];
    float h0 = act ? bf2f(h2b[(size_t)s0*40 + lane]) : 0.f;
    float h1 = act ? bf2f(h2b[(size_t)s1*40 + lane]) : 0.f;
    float h2 = act ? bf2f(h2b[(size_t)s2*40 + lane]) : 0.f;
    float h3 = act ? bf2f(h2b[(size_t)s3*40 + lane]) : 0.f;
    float h4 = act ? bf2f(h2b[(size_t)s4*40 + lane]) : 0.f;
    float h5 = act ? bf2f(h2b[(size_t)s5*40 + lane]) : 0.f;
    float h6 = act ? bf2f(h2b[(size_t)s6*40 + lane]) : 0.f;
    float h7 = act ? bf2f(h2b[(size_t)s7*40 + lane]) : 0.f;
    acc += e0*h0 + e1*h1 + e2*h2 + e3*h3 + e4*h4 + e5*h5 + e6*h6 + e7*h7;
    psum += (e0+e1+e2+e3) + (e4+e5+e6+e7);
  }
  for (; e < hi; ++e){
    int s0 = csr[e]; float e0 = ex2[e];
    acc += e0 * (act ? bf2f(h2b[(size_t)s0*40 + lane]) : 0.f);
    psum += e0;
  }
  float ov = acc/(psum + 1e-16f) + (act ? b2[lane] : 0.f);
  float v = act ? ov : -INFINITY;
  float mx = v;
  #pragma unroll
  for (int o=1;o<64;o<<=1) mx = fmaxf(mx, __shfl_xor(mx,o));
  float ev = act ? __expf(ov - mx) : 0.f;
  float se = ev;
  #pragma unroll
  for (int o=1;o<64;o<<=1) se += __shfl_xor(se,o);
  if (act) out[(size_t)node*40 + lane] = (ov - mx) - __logf(se);
}

extern "C" void kernel_launch(void* const* d_in, const int* in_sizes, int n_in,
                              void* d_out, int out_size, void* d_ws, size_t ws_size,
                              hipStream_t stream){
  const float* x   = (const float*)d_in[0];
  const int*   ei  = (const int*)d_in[1];     // [2,E] int32 (harness contract)
  const float* W1  = (const float*)d_in[2];
  const float* s1w = (const float*)d_in[3];
  const float* d1w = (const float*)d_in[4];
  const float* b1  = (const float*)d_in[5];
  const float* W2  = (const float*)d_in[6];
  const float* s2w = (const float*)d_in[7];
  const float* d2w = (const float*)d_in[8];
  const float* b2  = (const float*)d_in[9];
  float* out = (float*)d_out;

  const int N  = in_sizes[0] / 512;
  const int E  = in_sizes[1] / 2;
  const int Et = E + N;

  // workspace carve-out (~112 MB)
  float* f = (float*)d_ws;
  unsigned short* h1b   = (unsigned short*)f;  f += (size_t)N*128;   // [N][256] bf16
  unsigned short* hactb = (unsigned short*)f;  f += (size_t)N*128;   // [N][256] bf16
  float* as1  = f;  f += (size_t)N*4;
  float* ad1  = f;  f += (size_t)N*4;
  float* as2  = f;  f += N;
  float* ad2  = f;  f += N;
  unsigned short* w1t = (unsigned short*)f;  f += 256*512/2;         // [256][512] bf16
  unsigned short* xb  = (unsigned short*)f;  f += (size_t)N*256;     // [N][512] bf16 (51.2 MB)
  // aliases into dead xb region:
  unsigned short* h2b   = xb;                          // gemm2->agg2 ([N][40] bf16, 4 MB)
  float*          exbuf = (float*)(xb + (size_t)4*1024*1024);        // fill->agg1 ([Et][4] f32, 13.6 MB)
  float*          ex2   = (float*)(xb + (size_t)12*1024*1024);       // pre2->agg2 ([Et] f32, 3.4 MB)
  int* ip = (int*)f;
  int* rowstart = ip;  ip += (N + 4) & ~3;
  int* deg      = ip;  ip += N;
  int* cur      = ip;  ip += N;
  int* csr      = ip;  ip += Et;
  int* bsum     = ip;  ip += 256;

  int nb4 = (N + 3) / 4;
  int n4  = (N*512)/4;
  int nbs = (N + 255) / 256;                 // scan blocks (196 <= 256)
  k_cvt_x<<<(n4+255)/256, 256, 0, stream>>>(x, xb, n4);
  k_cvt_w<<<512, 256, 0, stream>>>(W1, w1t, deg, N);
  k_count<<<(Et+255)/256, 256, 0, stream>>>(ei, E, N, deg);
  k_scan_a<<<nbs, 256, 0, stream>>>(deg, rowstart, bsum, N);
  k_scan_b<<<1, 256, 0, stream>>>(bsum, nbs);
  k_scan_c<<<nbs, 256, 0, stream>>>(rowstart, bsum, cur, N);
  k_gemm1_mfma<<<dim3((N+127)/128, 2), 256, 0, stream>>>(xb, w1t, s1w, d1w, h1b, as1, ad1, N);
  k_fill <<<(Et+255)/256, 256, 0, stream>>>(ei, E, N, rowstart, cur, csr, as1, ad1, exbuf);
  k_agg1 <<<nb4, 256, 0, stream>>>(h1b, exbuf, rowstart, csr, b1, hactb, N);
  k_gemm2<<<(N+31)/32, 256, 0, stream>>>(hactb, W2, s2w, d2w, h2b, as2, ad2, N);
  k_pre2 <<<nb4, 256, 0, stream>>>(as2, ad2, rowstart, csr, ex2, N);
  k_agg2 <<<nb4, 256, 0, stream>>>(h2b, ex2, rowstart, csr, b2, out, N);
}

// Round 9
// 467.929 us; speedup vs baseline: 1.0693x; 1.0351x over previous
//
#include <hip/hip_runtime.h>
#include <math.h>
#include <stdint.h>

// GAT 2-layer: N=50000 nodes, E=800000 edges (+N self loops)
// L1: 512 -> 4 heads x 64 (bf16 MFMA GEMM reading fp32 x directly, cvt fused
//     into A-staging; att1 fused in epilogue), ELU.
// L2: 256 -> 1 head x 40 (att2 fused in gemm2), log_softmax.
// Softmax WITHOUT max-shift (logits ~N(0,1), clamped at 80): per-edge exp in
// k_fill (L1) / k_pre2 (L2); agg kernels consume wave-uniform scalar streams.

typedef short bf16x8 __attribute__((ext_vector_type(8)));
typedef float f32x4  __attribute__((ext_vector_type(4)));

static __device__ __forceinline__ float leaky(float x){ return x > 0.f ? x : 0.2f*x; }
static __device__ __forceinline__ unsigned short f2bf(float f){
  uint32_t u = __float_as_uint(f);
  uint32_t r = u + 0x7fffu + ((u >> 16) & 1u);   // RNE
  return (unsigned short)(r >> 16);
}
static __device__ __forceinline__ float bf2f(unsigned short u){
  return __uint_as_float(((uint32_t)u) << 16);
}

// ---------------- convert+transpose W1 -> w1t bf16; also zero deg ----------------
__global__ void k_cvt_w(const float* __restrict__ W, unsigned short* __restrict__ wt,
                        int* __restrict__ deg, int n){
  int i = blockIdx.x*blockDim.x + threadIdx.x;   // 0..131071
  if (i < n) deg[i] = 0;
  if (i >= 512*256) return;
  int k = i >> 8, c = i & 255;
  wt[c*512 + k] = f2bf(W[i]);
}

// ---------------- count in-degree (incl self loops) ----------------
__global__ void k_count(const int* __restrict__ ei, int E, int n, int* __restrict__ deg){
  int i = blockIdx.x*blockDim.x + threadIdx.x;
  int tot = E + n;
  if (i >= tot) return;
  int dst = (i < E) ? ei[E + i] : (i - E);
  atomicAdd(&deg[dst], 1);
}

// ---------------- multi-block exclusive scan: deg[n] -> rowstart[0..n] ----------------
__global__ __launch_bounds__(256) void k_scan_a(const int* __restrict__ deg,
    int* __restrict__ rowstart, int* __restrict__ bsum, int n){
  __shared__ int sm[256];
  int b = blockIdx.x, t = threadIdx.x;
  int i = b*256 + t;
  int v = (i < n) ? deg[i] : 0;
  sm[t] = v;
  __syncthreads();
  for (int off=1; off<256; off<<=1){
    int u = (t >= off) ? sm[t-off] : 0;
    __syncthreads();
    sm[t] += u;
    __syncthreads();
  }
  if (i < n) rowstart[i+1] = sm[t];
  if (t == 255) bsum[b] = sm[255];
}
__global__ __launch_bounds__(256) void k_scan_b(int* __restrict__ bsum, int nb){
  __shared__ int sm[256];
  int t = threadIdx.x;
  int v = (t < nb) ? bsum[t] : 0;
  sm[t] = v;
  __syncthreads();
  for (int off=1; off<256; off<<=1){
    int u = (t >= off) ? sm[t-off] : 0;
    __syncthreads();
    sm[t] += u;
    __syncthreads();
  }
  if (t < nb) bsum[t] = sm[t] - v;   // exclusive prefix
}
__global__ __launch_bounds__(256) void k_scan_c(int* __restrict__ rowstart,
    const int* __restrict__ bsum, int* __restrict__ cur, int n){
  int b = blockIdx.x, t = threadIdx.x;
  int i = b*256 + t;
  if (i < n){ rowstart[i+1] += bsum[b]; cur[i] = 0; }
  if (i == 0) rowstart[0] = 0;
}

// ---------------- GEMM1 (bf16 MFMA, fp32 A with fused cvt) + fused att1 ----------
__global__ __launch_bounds__(256) void k_gemm1_mfma(const float* __restrict__ X,
                                                    const unsigned short* __restrict__ BT,
                                                    const float* __restrict__ SW,
                                                    const float* __restrict__ DW,
                                                    unsigned short* __restrict__ Cb,
                                                    float* __restrict__ as1,
                                                    float* __restrict__ ad1, int M){
  __shared__ __align__(16) unsigned short lA[4*128*8];  // 8 KB
  __shared__ __align__(16) unsigned short lB[4*128*8];  // 8 KB
  const int t = threadIdx.x;
  const int lane = t & 63, w = t >> 6;
  const int wx = w & 1, wy = w >> 1;
  const int row0 = blockIdx.x * 128, col0 = blockIdx.y * 128;

  f32x4 acc[4][4];
  #pragma unroll
  for (int i=0;i<4;i++)
    #pragma unroll
    for (int j=0;j<4;j++)
      #pragma unroll
      for (int r=0;r<4;r++) acc[i][j][r] = 0.f;

  const int c0 = t, c1 = t + 256;
  const int r0 = c0 & 127, kq0 = c0 >> 7;     // kq0 in {0,1}
  const int r1 = c1 & 127, kq1 = c1 >> 7;     // kq1 in {2,3}
  const float* xA0 = X + (size_t)min(row0 + r0, M-1)*512 + kq0*8;
  const float* xA1 = X + (size_t)min(row0 + r1, M-1)*512 + kq1*8;
  const size_t gB0 = (size_t)(col0 + r0)*512 + kq0*8;
  const size_t gB1 = (size_t)(col0 + r1)*512 + kq1*8;

  const int kq = lane >> 4, li = lane & 15;

  for (int kt = 0; kt < 512; kt += 32){
    // B: async direct-to-LDS (bf16, pre-transposed)
    __builtin_amdgcn_global_load_lds((const __attribute__((address_space(1))) void*)(BT + gB0 + kt),
        (__attribute__((address_space(3))) void*)&lB[c0*8], 16, 0, 0);
    __builtin_amdgcn_global_load_lds((const __attribute__((address_space(1))) void*)(BT + gB1 + kt),
        (__attribute__((address_space(3))) void*)&lB[c1*8], 16, 0, 0);
    // A: fp32 load -> cvt bf16 -> LDS (fused k_cvt_x)
    float4 a00 = *(const float4*)(xA0 + kt);
    float4 a01 = *(const float4*)(xA0 + kt + 4);
    float4 a10 = *(const float4*)(xA1 + kt);
    float4 a11 = *(const float4*)(xA1 + kt + 4);
    bf16x8 p0, p1;
    p0[0]=(short)f2bf(a00.x); p0[1]=(short)f2bf(a00.y); p0[2]=(short)f2bf(a00.z); p0[3]=(short)f2bf(a00.w);
    p0[4]=(short)f2bf(a01.x); p0[5]=(short)f2bf(a01.y); p0[6]=(short)f2bf(a01.z); p0[7]=(short)f2bf(a01.w);
    p1[0]=(short)f2bf(a10.x); p1[1]=(short)f2bf(a10.y); p1[2]=(short)f2bf(a10.z); p1[3]=(short)f2bf(a10.w);
    p1[4]=(short)f2bf(a11.x); p1[5]=(short)f2bf(a11.y); p1[6]=(short)f2bf(a11.z); p1[7]=(short)f2bf(a11.w);
    *(bf16x8*)&lA[c0*8] = p0;
    *(bf16x8*)&lA[c1*8] = p1;
    __syncthreads();

    bf16x8 af[4], bfr[4];
    #pragma unroll
    for (int i=0;i<4;i++){
      af[i]  = *(const bf16x8*)&lA[(kq*128 + wx*64 + i*16 + li)*8];
      bfr[i] = *(const bf16x8*)&lB[(kq*128 + wy*64 + i*16 + li)*8];
    }
    #pragma unroll
    for (int i=0;i<4;i++)
      #pragma unroll
      for (int j=0;j<4;j++)
        acc[i][j] = __builtin_amdgcn_mfma_f32_16x16x32_bf16(af[i], bfr[j], acc[i][j], 0, 0, 0);
    __syncthreads();
  }

  // epilogue 1: C store. C/D map col=lane&15, row=(lane>>4)*4+reg
  #pragma unroll
  for (int i=0;i<4;i++){
    #pragma unroll
    for (int r=0;r<4;r++){
      int row = row0 + wx*64 + i*16 + kq*4 + r;
      if (row < M){
        #pragma unroll
        for (int j=0;j<4;j++)
          Cb[(size_t)row*256 + col0 + wy*64 + j*16 + li] = f2bf(acc[i][j][r]);
      }
    }
  }

  // epilogue 2: fused att1 dots for head hw (this wave's 64-col span)
  const int hw = (int)blockIdx.y*2 + wy;
  float sv[4], dv[4];
  #pragma unroll
  for (int j=0;j<4;j++){
    sv[j] = SW[hw*64 + j*16 + li];
    dv[j] = DW[hw*64 + j*16 + li];
  }
  #pragma unroll
  for (int i=0;i<4;i++){
    #pragma unroll
    for (int r=0;r<4;r++){
      float ps = acc[i][0][r]*sv[0] + acc[i][1][r]*sv[1] + acc[i][2][r]*sv[2] + acc[i][3][r]*sv[3];
      float pd = acc[i][0][r]*dv[0] + acc[i][1][r]*dv[1] + acc[i][2][r]*dv[2] + acc[i][3][r]*dv[3];
      #pragma unroll
      for (int o=1;o<16;o<<=1){ ps += __shfl_xor(ps,o); pd += __shfl_xor(pd,o); }
      int row = row0 + wx*64 + i*16 + kq*4 + r;
      if (li == 0 && row < M){
        as1[row*4 + hw] = ps;
        ad1[row*4 + hw] = pd;
      }
    }
  }
}

// ---------------- scatter edges into CSR + compute per-edge ex (4 heads) ----------
__global__ void k_fill(const int* __restrict__ ei, int E, int n,
                       const int* __restrict__ rowstart, int* __restrict__ cur,
                       int* __restrict__ csr,
                       const float* __restrict__ as1, const float* __restrict__ ad1,
                       float* __restrict__ exbuf){
  int i = blockIdx.x*blockDim.x + threadIdx.x;
  int tot = E + n;
  if (i >= tot) return;
  int src, dst;
  if (i < E){ src = ei[i]; dst = ei[E+i]; } else { src = i - E; dst = src; }
  int pos = atomicAdd(&cur[dst], 1);
  int slot = rowstart[dst] + pos;
  csr[slot] = src;
  float4 a = *(const float4*)(as1 + (size_t)src*4);
  float4 d = *(const float4*)(ad1 + (size_t)dst*4);
  float4 ex;
  ex.x = __expf(fminf(leaky(a.x + d.x), 80.f));
  ex.y = __expf(fminf(leaky(a.y + d.y), 80.f));
  ex.z = __expf(fminf(leaky(a.z + d.z), 80.f));
  ex.w = __expf(fminf(leaky(a.w + d.w), 80.f));
  *(float4*)(exbuf + (size_t)slot*4) = ex;
}

// ---------------- aggregation L1: pure gather+fma, denom inline, + bias + ELU ----------
__global__ __launch_bounds__(256) void k_agg1(const unsigned short* __restrict__ h1b,
    const float* __restrict__ exbuf,
    const int* __restrict__ rowstart, const int* __restrict__ csr,
    const float* __restrict__ b1, unsigned short* __restrict__ hactb, int n){
  int lane = threadIdx.x & 63;
  int node = blockIdx.x*4 + (threadIdx.x >> 6);
  if (node >= n) return;
  int lo = __builtin_amdgcn_readfirstlane(rowstart[node]);
  int hi = __builtin_amdgcn_readfirstlane(rowstart[node+1]);
  int h = lane >> 4;
  const float* exb = exbuf + h;          // lane reads exbuf[e*4+h]
  float ax=0.f, ay=0.f, az=0.f, aw=0.f, psum=0.f;
  int e = lo;
  for (; e + 7 < hi; e += 8){
    int s0 = csr[e],   s1 = csr[e+1], s2 = csr[e+2], s3 = csr[e+3];   // scalar
    int s4 = csr[e+4], s5 = csr[e+5], s6 = csr[e+6], s7 = csr[e+7];
    float e0 = exb[(size_t)e*4],     e1 = exb[(size_t)(e+1)*4],
          e2 = exb[(size_t)(e+2)*4], e3 = exb[(size_t)(e+3)*4],
          e4 = exb[(size_t)(e+4)*4], e5 = exb[(size_t)(e+5)*4],
          e6 = exb[(size_t)(e+6)*4], e7 = exb[(size_t)(e+7)*4];
    ushort4 u0 = *(const ushort4*)(h1b + (size_t)s0*256 + lane*4);
    ushort4 u1 = *(const ushort4*)(h1b + (size_t)s1*256 + lane*4);
    ushort4 u2 = *(const ushort4*)(h1b + (size_t)s2*256 + lane*4);
    ushort4 u3 = *(const ushort4*)(h1b + (size_t)s3*256 + lane*4);
    ushort4 u4 = *(const ushort4*)(h1b + (size_t)s4*256 + lane*4);
    ushort4 u5 = *(const ushort4*)(h1b + (size_t)s5*256 + lane*4);
    ushort4 u6 = *(const ushort4*)(h1b + (size_t)s6*256 + lane*4);
    ushort4 u7 = *(const ushort4*)(h1b + (size_t)s7*256 + lane*4);
    ax += e0*bf2f(u0.x) + e1*bf2f(u1.x) + e2*bf2f(u2.x) + e3*bf2f(u3.x)
        + e4*bf2f(u4.x) + e5*bf2f(u5.x) + e6*bf2f(u6.x) + e7*bf2f(u7.x);
    ay += e0*bf2f(u0.y) + e1*bf2f(u1.y) + e2*bf2f(u2.y) + e3*bf2f(u3.y)
        + e4*bf2f(u4.y) + e5*bf2f(u5.y) + e6*bf2f(u6.y) + e7*bf2f(u7.y);
    az += e0*bf2f(u0.z) + e1*bf2f(u1.z) + e2*bf2f(u2.z) + e3*bf2f(u3.z)
        + e4*bf2f(u4.z) + e5*bf2f(u5.z) + e6*bf2f(u6.z) + e7*bf2f(u7.z);
    aw += e0*bf2f(u0.w) + e1*bf2f(u1.w) + e2*bf2f(u2.w) + e3*bf2f(u3.w)
        + e4*bf2f(u4.w) + e5*bf2f(u5.w) + e6*bf2f(u6.w) + e7*bf2f(u7.w);
    psum += (e0+e1+e2+e3) + (e4+e5+e6+e7);
  }
  for (; e < hi; ++e){
    int s0 = csr[e];
    float e0 = exb[(size_t)e*4];
    ushort4 u0 = *(const ushort4*)(h1b + (size_t)s0*256 + lane*4);
    ax += e0*bf2f(u0.x); ay += e0*bf2f(u0.y); az += e0*bf2f(u0.z); aw += e0*bf2f(u0.w);
    psum += e0;
  }
  float inv = 1.f/(psum + 1e-16f);
  float4 bv = *(const float4*)(b1 + lane*4);
  float o0 = ax*inv + bv.x, o1 = ay*inv + bv.y, o2 = az*inv + bv.z, o3 = aw*inv + bv.w;
  ushort4 r;
  r.x = f2bf(o0 > 0.f ? o0 : expm1f(o0));
  r.y = f2bf(o1 > 0.f ? o1 : expm1f(o1));
  r.z = f2bf(o2 > 0.f ? o2 : expm1f(o2));
  r.w = f2bf(o3 > 0.f ? o3 : expm1f(o3));
  *(ushort4*)(hactb + (size_t)node*256 + lane*4) = r;
}

// ---------------- GEMM2: hact[M,256]bf16 @ W2[256,40]f32 -> h2b[M,40]bf16 ------------
// + fused att2: as2/ad2 [N] via LDS reduce.
__global__ __launch_bounds__(256) void k_gemm2(const unsigned short* __restrict__ A,
    const float* __restrict__ B, const float* __restrict__ sw, const float* __restrict__ dw,
    unsigned short* __restrict__ Cb, float* __restrict__ as2, float* __restrict__ ad2, int M){
  __shared__ float Xl[32][129];       // pad -> conflict-free column reads
  __shared__ float Wl[128*40];
  __shared__ float Sps[32][8], Spd[32][8];
  int t = threadIdx.x;
  int row0 = blockIdx.x*32;
  int r = t & 31, g = t >> 5;         // g in 0..7 -> cols g*5 .. g*5+4
  float acc[5] = {0,0,0,0,0};
  for (int kt=0; kt<256; kt+=128){
    for (int i=t; i<1280; i+=256)
      *(float4*)&Wl[i*4] = *(const float4*)(B + kt*40 + i*4);
    for (int i=t; i<512; i+=256){     // 32 rows x 128 k, 8 bf16 per chunk
      int rr = i >> 4, k8 = i & 15;
      int grow = row0 + rr; if (grow >= M) grow = M-1;
      uint4 v = *(const uint4*)(A + (size_t)grow*256 + kt + k8*8);
      float* xp = &Xl[rr][k8*8];
      xp[0] = __uint_as_float(v.x << 16); xp[1] = __uint_as_float(v.x & 0xffff0000u);
      xp[2] = __uint_as_float(v.y << 16); xp[3] = __uint_as_float(v.y & 0xffff0000u);
      xp[4] = __uint_as_float(v.z << 16); xp[5] = __uint_as_float(v.z & 0xffff0000u);
      xp[6] = __uint_as_float(v.w << 16); xp[7] = __uint_as_float(v.w & 0xffff0000u);
    }
    __syncthreads();
    #pragma unroll 4
    for (int k=0;k<128;++k){
      float a = Xl[r][k];
      const float* wp = &Wl[k*40 + g*5];
      #pragma unroll
      for (int j=0;j<5;++j) acc[j] += a * wp[j];
    }
    __syncthreads();
  }
  int grow = row0 + r;
  float ps = 0.f, pd = 0.f;
  #pragma unroll
  for (int j=0;j<5;++j){
    ps += acc[j] * sw[g*5+j];
    pd += acc[j] * dw[g*5+j];
  }
  Sps[r][g] = ps; Spd[r][g] = pd;
  if (grow < M){
    #pragma unroll
    for (int j=0;j<5;++j) Cb[(size_t)grow*40 + g*5 + j] = f2bf(acc[j]);
  }
  __syncthreads();
  if (t < 32){
    float a = 0.f, b = 0.f;
    #pragma unroll
    for (int g2=0; g2<8; ++g2){ a += Sps[t][g2]; b += Spd[t][g2]; }
    int rw = row0 + t;
    if (rw < M){ as2[rw] = a; ad2[rw] = b; }
  }
}

// ---------------- pre-pass L2: per-edge ex (no max, single pass) ----------------
__global__ __launch_bounds__(256) void k_pre2(const float* __restrict__ as2,
    const float* __restrict__ ad2, const int* __restrict__ rowstart,
    const int* __restrict__ csr, float* __restrict__ ex2, int n){
  int lane = threadIdx.x & 63;
  int node = blockIdx.x*4 + (threadIdx.x >> 6);
  if (node >= n) return;
  int lo = rowstart[node], hi = rowstart[node+1];
  float adn = ad2[node];
  for (int e = lo + lane; e < hi; e += 64)
    ex2[e] = __expf(fminf(leaky(as2[csr[e]] + adn), 80.f));
}

// ---------------- aggregation L2: gather+fma, denom inline, + bias + log_softmax ------
__global__ __launch_bounds__(256) void k_agg2(const unsigned short* __restrict__ h2b,
    const float* __restrict__ ex2,
    const int* __restrict__ rowstart, const int* __restrict__ csr,
    const float* __restrict__ b2, float* __restrict__ out, int n){
  int lane = threadIdx.x & 63;
  int node = blockIdx.x*4 + (threadIdx.x >> 6);
  if (node >= n) return;
  int lo = __builtin_amdgcn_readfirstlane(rowstart[node]);
  int hi = __builtin_amdgcn_readfirstlane(rowstart[node+1]);
  bool act = lane < 40;
  float acc = 0.f, psum = 0.f;
  int e = lo;
  for (; e + 7 < hi; e += 8){
    int s0 = csr[e],   s1 = csr[e+1], s2 = csr[e+2], s3 = csr[e+3];   // scalar
    int s4 = csr[e+4], s5 = csr[e+5], s6 = csr[e+6], s7 = csr[e+7];
    float e0 = ex2[e],   e1 = ex2[e+1], e2 = ex2[e+2], e3 = ex2[e+3]; // scalar
    float e4 = ex2[e+4], e5 = ex2[e+5], e6 = ex2[e+6], e7 = ex2[e+7];
    float h0 = act ? bf2f(h2b[(size_t)s0*40 + lane]) : 0.f;
    float h1 = act ? bf2f(h2b[(size_t)s1*40 + lane]) : 0.f;
    float h2 = act ? bf2f(h2b[(size_t)s2*40 + lane]) : 0.f;
    float h3 = act ? bf2f(h2b[(size_t)s3*40 + lane]) : 0.f;
    float h4 = act ? bf2f(h2b[(size_t)s4*40 + lane]) : 0.f;
    float h5 = act ? bf2f(h2b[(size_t)s5*40 + lane]) : 0.f;
    float h6 = act ? bf2f(h2b[(size_t)s6*40 + lane]) : 0.f;
    float h7 = act ? bf2f(h2b[(size_t)s7*40 + lane]) : 0.f;
    acc += e0*h0 + e1*h1 + e2*h2 + e3*h3 + e4*h4 + e5*h5 + e6*h6 + e7*h7;
    psum += (e0+e1+e2+e3) + (e4+e5+e6+e7);
  }
  for (; e < hi; ++e){
    int s0 = csr[e]; float e0 = ex2[e];
    acc += e0 * (act ? bf2f(h2b[(size_t)s0*40 + lane]) : 0.f);
    psum += e0;
  }
  float ov = acc/(psum + 1e-16f) + (act ? b2[lane] : 0.f);
  float v = act ? ov : -INFINITY;
  float mx = v;
  #pragma unroll
  for (int o=1;o<64;o<<=1) mx = fmaxf(mx, __shfl_xor(mx,o));
  float ev = act ? __expf(ov - mx) : 0.f;
  float se = ev;
  #pragma unroll
  for (int o=1;o<64;o<<=1) se += __shfl_xor(se,o);
  if (act) out[(size_t)node*40 + lane] = (ov - mx) - __logf(se);
}

extern "C" void kernel_launch(void* const* d_in, const int* in_sizes, int n_in,
                              void* d_out, int out_size, void* d_ws, size_t ws_size,
                              hipStream_t stream){
  const float* x   = (const float*)d_in[0];
  const int*   ei  = (const int*)d_in[1];     // [2,E] int32 (harness contract)
  const float* W1  = (const float*)d_in[2];
  const float* s1w = (const float*)d_in[3];
  const float* d1w = (const float*)d_in[4];
  const float* b1  = (const float*)d_in[5];
  const float* W2  = (const float*)d_in[6];
  const float* s2w = (const float*)d_in[7];
  const float* d2w = (const float*)d_in[8];
  const float* b2  = (const float*)d_in[9];
  float* out = (float*)d_out;

  const int N  = in_sizes[0] / 512;
  const int E  = in_sizes[1] / 2;
  const int Et = E + N;

  // workspace carve-out (~80 MB)
  float* f = (float*)d_ws;
  unsigned short* h1b   = (unsigned short*)f;  f += (size_t)N*128;   // [N][256] bf16
  unsigned short* hactb = (unsigned short*)f;  f += (size_t)N*128;   // [N][256] bf16
  float* as1  = f;  f += (size_t)N*4;
  float* ad1  = f;  f += (size_t)N*4;
  float* as2  = f;  f += N;
  float* ad2  = f;  f += N;
  unsigned short* w1t = (unsigned short*)f;  f += 256*512/2;         // [256][512] bf16
  unsigned short* h2b = (unsigned short*)f;  f += (size_t)N*40/2 + 64; // [N][40] bf16
  float* exbuf = f;  f += (size_t)Et*4;                              // [Et][4] f32
  float* ex2   = f;  f += Et;                                        // [Et] f32
  int* ip = (int*)f;
  int* rowstart = ip;  ip += (N + 4) & ~3;
  int* deg      = ip;  ip += N;
  int* cur      = ip;  ip += N;
  int* csr      = ip;  ip += Et;
  int* bsum     = ip;  ip += 256;

  int nb4 = (N + 3) / 4;
  int nbs = (N + 255) / 256;                 // scan blocks (196 <= 256)
  k_cvt_w<<<512, 256, 0, stream>>>(W1, w1t, deg, N);
  k_count<<<(Et+255)/256, 256, 0, stream>>>(ei, E, N, deg);
  k_scan_a<<<nbs, 256, 0, stream>>>(deg, rowstart, bsum, N);
  k_scan_b<<<1, 256, 0, stream>>>(bsum, nbs);
  k_scan_c<<<nbs, 256, 0, stream>>>(rowstart, bsum, cur, N);
  k_gemm1_mfma<<<dim3((N+127)/128, 2), 256, 0, stream>>>(x, w1t, s1w, d1w, h1b, as1, ad1, N);
  k_fill <<<(Et+255)/256, 256, 0, stream>>>(ei, E, N, rowstart, cur, csr, as1, ad1, exbuf);
  k_agg1 <<<nb4, 256, 0, stream>>>(h1b, exbuf, rowstart, csr, b1, hactb, N);
  k_gemm2<<<(N+31)/32, 256, 0, stream>>>(hactb, W2, s2w, d2w, h2b, as2, ad2, N);
  k_pre2 <<<nb4, 256, 0, stream>>>(as2, ad2, rowstart, csr, ex2, N);
  k_agg2 <<<nb4, 256, 0, stream>>>(h2b, ex2, rowstart, csr, b2, out, N);
}